// Round 4
// baseline (314.008 us; speedup 1.0000x reference)
//
#include <hip/hip_runtime.h>
#include <hip/hip_bf16.h>

static constexpr int BATCH = 16384;
static constexpr int DIM   = 1024;
static constexpr int NN    = 1024;
static constexpr int G     = 32;

typedef _Float16 half8  __attribute__((ext_vector_type(8)));
typedef _Float16 half4v __attribute__((ext_vector_type(4)));
typedef float    f32x4  __attribute__((ext_vector_type(4)));

// ---------------------------------------------------------------------------
// prep: w -> fp16 copy + coalesced fp16 transpose + wsq partials via atomics.
// grid 256 blocks (16 n-tiles x 16 d-tiles), 256 threads. wsq pre-zeroed.
// ---------------------------------------------------------------------------
__global__ __launch_bounds__(256) void transpose_w_kernel(const float* __restrict__ W,
                                                          _Float16* __restrict__ Wh,
                                                          _Float16* __restrict__ WTh,
                                                          float* __restrict__ wsq) {
    __shared__ _Float16 tile[64][72];
    const int t  = threadIdx.x;
    const int n0 = (blockIdx.x & 15) * 64;
    const int d0 = (blockIdx.x >> 4) * 64;
#pragma unroll
    for (int p = 0; p < 4; ++p) {
        int n = n0 + p * 16 + (t >> 4);
        int d = d0 + (t & 15) * 4;
        float4 v = *(const float4*)(W + (size_t)n * DIM + d);
        half4v h;
        h[0] = (_Float16)v.x; h[1] = (_Float16)v.y;
        h[2] = (_Float16)v.z; h[3] = (_Float16)v.w;
        *(half4v*)(Wh + (size_t)n * DIM + d) = h;
#pragma unroll
        for (int k = 0; k < 4; ++k)
            tile[(t & 15) * 4 + k][p * 16 + (t >> 4)] = h[k];
        float ss = v.x * v.x + v.y * v.y + v.z * v.z + v.w * v.w;
        ss += __shfl_xor(ss, 1, 64);
        ss += __shfl_xor(ss, 2, 64);
        ss += __shfl_xor(ss, 4, 64);
        ss += __shfl_xor(ss, 8, 64);
        if ((t & 15) == 0) atomicAdd(wsq + n, ss);
    }
    __syncthreads();
#pragma unroll
    for (int p = 0; p < 4; ++p) {
        int dp = p * 16 + (t >> 4);
        int nc = (t & 15) * 4;
        half4v hv = *(const half4v*)&tile[dp][nc];
        *(half4v*)(WTh + (size_t)(d0 + dp) * NN + n0 + nc) = hv;
    }
}

// ---------------------------------------------------------------------------
// Fused: logits GEMM (32 rows x all 1024 nodes) + dual softmax + normalize,
// writing fp16 combined weights directly.  Grid 512 blocks x 256 thr.
// Per wave: 32 rows x 256-node strip; acc[2][16] f32x4.
// A (x, fp32) staged via 8KB LDS dbuf with inline cvt; B (wh) streamed from L2.
// ---------------------------------------------------------------------------
__global__ __launch_bounds__(256, 2) void fused1_kernel(const float* __restrict__ X,
                                                        const _Float16* __restrict__ Wh,
                                                        const float* __restrict__ wsq,
                                                        _Float16* __restrict__ Ch) {
    __shared__ __align__(16) _Float16 As[2][32 * 64];
    __shared__ float st[4][32][32];     // cross-wave softmax partials (16 KB)
    __shared__ float rowtot[4][32];

    const int t  = threadIdx.x;
    const int l  = t & 63;
    const int wv = t >> 6;
    const int b0 = blockIdx.x * 32;

    // A staging: thread -> (row, 8-k chunk), swizzled chunk slot = c ^ (row&7)
    const int srow = t >> 3;            // 0..31
    const int schk = t & 7;             // 0..7
    const int soff = srow * 64 + ((schk ^ (srow & 7)) * 8);
    const float* xrow = X + (size_t)(b0 + srow) * DIM + schk * 8;

    const int nbase = wv * 256 + (l & 15);    // + 16*ni = node id
    const int kfrag = (l >> 4) * 8;

    f32x4 acc[2][16] = {};

    float4 pa = *(const float4*)(xrow);
    float4 pb = *(const float4*)(xrow + 4);

    auto writeA = [&](int buf, float4 a, float4 b) {
        half8 h;
        h[0] = (_Float16)a.x; h[1] = (_Float16)a.y;
        h[2] = (_Float16)a.z; h[3] = (_Float16)a.w;
        h[4] = (_Float16)b.x; h[5] = (_Float16)b.y;
        h[6] = (_Float16)b.z; h[7] = (_Float16)b.w;
        *(half8*)(&As[buf][soff]) = h;
    };
    writeA(0, pa, pb);

    int p = 0;
    for (int kt = 0; kt < DIM; kt += 64, p ^= 1) {
        __syncthreads();
        if (kt + 64 < DIM) {
            pa = *(const float4*)(xrow + kt + 64);
            pb = *(const float4*)(xrow + kt + 64 + 4);
        }
#pragma unroll
        for (int sub = 0; sub < 2; ++sub) {
            const int ck = (sub * 4 + (l >> 4)) ^ (l & 7);
            half8 af0 = *(const half8*)(&As[p][(l & 15) * 64 + ck * 8]);
            half8 af1 = *(const half8*)(&As[p][((l & 15) + 16) * 64 + ck * 8]);
#pragma unroll
            for (int ni = 0; ni < 16; ++ni) {
                const _Float16* gb = Wh + (size_t)(nbase + 16 * ni) * DIM + kt + sub * 32 + kfrag;
                half8 bf = *(const half8*)gb;
                acc[0][ni] = __builtin_amdgcn_mfma_f32_16x16x32_f16(af0, bf, acc[0][ni], 0, 0, 0);
                acc[1][ni] = __builtin_amdgcn_mfma_f32_16x16x32_f16(af1, bf, acc[1][ni], 0, 0, 0);
            }
        }
        if (kt + 64 < DIM) writeA(p ^ 1, pa, pb);
    }

    // ---- logits in-place: Lv = 2*acc - wsq[n]   (||x||^2 cancels in both softmaxes)
#pragma unroll
    for (int ni = 0; ni < 16; ++ni) {
        float wq = wsq[nbase + 16 * ni];
#pragma unroll
        for (int mi = 0; mi < 2; ++mi)
#pragma unroll
            for (int r = 0; r < 4; ++r)
                acc[mi][ni][r] = 2.f * acc[mi][ni][r] - wq;
    }
    // layout: value (mi,ni,r) is at row b = mi*16+(l>>4)*4+r, node n = nbase+16*ni
    //   g1 = n>>5 = wv*8 + (ni>>1);  g2 = n&31 = (ni&1)*16 + (l&15)

    // ---- axis-2 softmax offsets o2 = m + ln(sum), per (row, g1): in-wave
    float o2[2][8][4];
#pragma unroll
    for (int mi = 0; mi < 2; ++mi)
#pragma unroll
        for (int n1 = 0; n1 < 8; ++n1)
#pragma unroll
            for (int r = 0; r < 4; ++r) {
                float m = fmaxf(acc[mi][2 * n1][r], acc[mi][2 * n1 + 1][r]);
                m = fmaxf(m, __shfl_xor(m, 1, 64));
                m = fmaxf(m, __shfl_xor(m, 2, 64));
                m = fmaxf(m, __shfl_xor(m, 4, 64));
                m = fmaxf(m, __shfl_xor(m, 8, 64));
                float s = __expf(acc[mi][2 * n1][r] - m) + __expf(acc[mi][2 * n1 + 1][r] - m);
                s += __shfl_xor(s, 1, 64);
                s += __shfl_xor(s, 2, 64);
                s += __shfl_xor(s, 4, 64);
                s += __shfl_xor(s, 8, 64);
                o2[mi][n1][r] = m + __logf(s);
            }

    // ---- axis-1 softmax offsets o1 = m + ln(sum), per (row, g2): cross-wave via LDS
    float mfin[2][2][4], o1[2][2][4];
#pragma unroll
    for (int mi = 0; mi < 2; ++mi)
#pragma unroll
        for (int n0 = 0; n0 < 2; ++n0)
#pragma unroll
            for (int r = 0; r < 4; ++r) {
                float m = -1e30f;
#pragma unroll
                for (int n1 = 0; n1 < 8; ++n1)
                    m = fmaxf(m, acc[mi][2 * n1 + n0][r]);
                st[wv][mi * 16 + (l >> 4) * 4 + r][n0 * 16 + (l & 15)] = m;
            }
    __syncthreads();
#pragma unroll
    for (int mi = 0; mi < 2; ++mi)
#pragma unroll
        for (int n0 = 0; n0 < 2; ++n0)
#pragma unroll
            for (int r = 0; r < 4; ++r) {
                int b = mi * 16 + (l >> 4) * 4 + r, g2 = n0 * 16 + (l & 15);
                mfin[mi][n0][r] = fmaxf(fmaxf(st[0][b][g2], st[1][b][g2]),
                                        fmaxf(st[2][b][g2], st[3][b][g2]));
            }
    __syncthreads();
#pragma unroll
    for (int mi = 0; mi < 2; ++mi)
#pragma unroll
        for (int n0 = 0; n0 < 2; ++n0)
#pragma unroll
            for (int r = 0; r < 4; ++r) {
                float s = 0.f;
#pragma unroll
                for (int n1 = 0; n1 < 8; ++n1)
                    s += __expf(acc[mi][2 * n1 + n0][r] - mfin[mi][n0][r]);
                st[wv][mi * 16 + (l >> 4) * 4 + r][n0 * 16 + (l & 15)] = s;
            }
    __syncthreads();
#pragma unroll
    for (int mi = 0; mi < 2; ++mi)
#pragma unroll
        for (int n0 = 0; n0 < 2; ++n0)
#pragma unroll
            for (int r = 0; r < 4; ++r) {
                int b = mi * 16 + (l >> 4) * 4 + r, g2 = n0 * 16 + (l & 15);
                float s = st[0][b][g2] + st[1][b][g2] + st[2][b][g2] + st[3][b][g2];
                o1[mi][n0][r] = mfin[mi][n0][r] + __logf(s);
            }

    // ---- combine: c = exp(2*Lv - o2 - o1), row-normalize, store fp16
    float tot[2][4] = {};
#pragma unroll
    for (int mi = 0; mi < 2; ++mi)
#pragma unroll
        for (int ni = 0; ni < 16; ++ni)
#pragma unroll
            for (int r = 0; r < 4; ++r) {
                float c = __expf(2.f * acc[mi][ni][r] - o2[mi][ni >> 1][r] - o1[mi][ni & 1][r]);
                acc[mi][ni][r] = c;
                tot[mi][r] += c;
            }
#pragma unroll
    for (int mi = 0; mi < 2; ++mi)
#pragma unroll
        for (int r = 0; r < 4; ++r) {
            float s = tot[mi][r];
            s += __shfl_xor(s, 1, 64);
            s += __shfl_xor(s, 2, 64);
            s += __shfl_xor(s, 4, 64);
            s += __shfl_xor(s, 8, 64);
            tot[mi][r] = s;
        }
    if ((l & 15) == 0)
#pragma unroll
        for (int mi = 0; mi < 2; ++mi)
#pragma unroll
            for (int r = 0; r < 4; ++r)
                rowtot[wv][mi * 16 + (l >> 4) * 4 + r] = tot[mi][r];
    __syncthreads();
    float inv[2][4];
#pragma unroll
    for (int mi = 0; mi < 2; ++mi)
#pragma unroll
        for (int r = 0; r < 4; ++r) {
            int b = mi * 16 + (l >> 4) * 4 + r;
            inv[mi][r] = 1.f / (rowtot[0][b] + rowtot[1][b] + rowtot[2][b] + rowtot[3][b] + 1e-8f);
        }
#pragma unroll
    for (int mi = 0; mi < 2; ++mi)
#pragma unroll
        for (int r = 0; r < 4; ++r) {
            size_t row = b0 + mi * 16 + (l >> 4) * 4 + r;
#pragma unroll
            for (int ni = 0; ni < 16; ++ni)
                Ch[row * NN + nbase + 16 * ni] = (_Float16)(acc[mi][ni][r] * inv[mi][r]);
        }
}

// ---------------------------------------------------------------------------
// GEMM2 (R2-measured structure, BK=32): out = ch @ wth^T
// 128x128 tile, XOR-swizzled LDS, XCD-aware tile swizzle.
// ---------------------------------------------------------------------------
__global__ __launch_bounds__(256) void gemm2_kernel(const _Float16* __restrict__ A,
                                                    const _Float16* __restrict__ B,
                                                    float* __restrict__ C,
                                                    int M, int N, int K) {
    __shared__ __align__(16) _Float16 As[128 * 32];
    __shared__ __align__(16) _Float16 Bs[128 * 32];

    const int t  = threadIdx.x;
    const int l  = t & 63;
    const int wv = t >> 6;

    const int NT  = N >> 7;
    const int MT  = M >> 7;
    const int lid = blockIdx.x;
    const int xcd = lid & 7;
    const int i0  = lid >> 3;
    const int bn  = (i0 % NT) * 128;
    const int bm  = (xcd * (MT >> 3) + i0 / NT) * 128;

    const int wm = (wv >> 1) * 64;
    const int wn = (wv & 1) * 64;

    const int srow = (l >> 2);
    const int skk  = (((l & 3) ^ ((srow >> 1) & 3)) * 8);

    auto stage = [&](int k0) {
#pragma unroll
        for (int j = 0; j < 2; ++j) {
            int rbase = wv * 32 + j * 16;
            const _Float16* gA = A + (size_t)(bm + rbase + srow) * K + k0 + skk;
            __builtin_amdgcn_global_load_lds(
                (const __attribute__((address_space(1))) void*)gA,
                (__attribute__((address_space(3))) void*)(As + rbase * 32), 16, 0, 0);
            const _Float16* gB = B + (size_t)(bn + rbase + srow) * K + k0 + skk;
            __builtin_amdgcn_global_load_lds(
                (const __attribute__((address_space(1))) void*)gB,
                (__attribute__((address_space(3))) void*)(Bs + rbase * 32), 16, 0, 0);
        }
    };

    f32x4 acc[4][4] = {};
    stage(0);
    const int xr   = ((l & 15) >> 1) & 3;
    const int kqs  = (((l >> 4) ^ xr) * 8);
    const int mrow = wm + (l & 15);
    const int ncol = wn + (l & 15);

    for (int kt = 0; kt < K; kt += 32) {
        __syncthreads();
        half8 af[4], bf[4];
#pragma unroll
        for (int mi = 0; mi < 4; ++mi)
            af[mi] = *(const half8*)(As + (mrow + mi * 16) * 32 + kqs);
#pragma unroll
        for (int ni = 0; ni < 4; ++ni)
            bf[ni] = *(const half8*)(Bs + (ncol + ni * 16) * 32 + kqs);
#pragma unroll
        for (int mi = 0; mi < 4; ++mi)
#pragma unroll
            for (int ni = 0; ni < 4; ++ni)
                acc[mi][ni] = __builtin_amdgcn_mfma_f32_16x16x32_f16(
                    af[mi], bf[ni], acc[mi][ni], 0, 0, 0);
        __syncthreads();
        if (kt + 32 < K) stage(kt + 32);
    }

#pragma unroll
    for (int mi = 0; mi < 4; ++mi) {
        const int rbase = bm + wm + mi * 16 + (l >> 4) * 4;
#pragma unroll
        for (int ni = 0; ni < 4; ++ni) {
            const int col = bn + wn + ni * 16 + (l & 15);
#pragma unroll
            for (int r = 0; r < 4; ++r)
                C[(size_t)(rbase + r) * N + col] = acc[mi][ni][r];
        }
    }
}

// ---------------------------------------------------------------------------
extern "C" void kernel_launch(void* const* d_in, const int* in_sizes, int n_in,
                              void* d_out, int out_size, void* d_ws, size_t ws_size,
                              hipStream_t stream) {
    const float* x = (const float*)d_in[0];
    const float* w = (const float*)d_in[1];
    float* out = (float*)d_out;

    char* ws = (char*)d_ws;
    size_t off = 0;
    _Float16* ch  = (_Float16*)(ws + off); off += (size_t)BATCH * NN * 2;  // 32 MB
    _Float16* wh  = (_Float16*)(ws + off); off += (size_t)NN * DIM * 2;    // 2 MB
    _Float16* wth = (_Float16*)(ws + off); off += (size_t)DIM * NN * 2;    // 2 MB
    float*    wsq = (float*)   (ws + off); off += (size_t)NN * 4;

    hipMemsetAsync(wsq, 0, NN * sizeof(float), stream);
    // 1. w prep: fp16 copy + transpose + wsq
    transpose_w_kernel<<<256, 256, 0, stream>>>(w, wh, wth, wsq);
    // 2. fused logits-GEMM + dual softmax -> ch (fp16)
    fused1_kernel<<<BATCH / 32, 256, 0, stream>>>(x, wh, wsq, ch);
    // 3. recon = ch @ w  (B = wth, K-contiguous)
    gemm2_kernel<<<(BATCH / 128) * (DIM / 128), 256, 0, stream>>>(
        ch, wth, out, BATCH, DIM, NN);
}